// Round 1
// baseline (767.911 us; speedup 1.0000x reference)
//
#include <hip/hip_runtime.h>
#include <hip/hip_bf16.h>

// Bahdanau additive attention, MI355X.
// B=32, S=2048, E=D=1024. M = B*S = 65536.
// scores[m] = v . tanh(enc[m,:] @ w1 + qq[b]),  qq[b] = dec[b] @ w2 + b2 + b1
// (bv dropped: constant shift is softmax-invariant)
// attn = softmax_s(scores); context[b] = attn[b,:] @ enc[b,:,:]

typedef __attribute__((ext_vector_type(8))) short short8;   // 8 bf16 (4 VGPRs)
typedef __attribute__((ext_vector_type(4))) float f32x4;    // MFMA acc

#define M_TOTAL 65536
#define NDIM    1024
#define KDIM    1024
#define LDSP    40   // padded row stride (ushorts) -> 80B, breaks b128 bank conflicts

static __device__ inline unsigned int pk2(float a, float b) {
    __hip_bfloat16 ha = __float2bfloat16(a);
    __hip_bfloat16 hb = __float2bfloat16(b);
    unsigned short ua, ub;
    __builtin_memcpy(&ua, &ha, 2);
    __builtin_memcpy(&ub, &hb, 2);
    return (unsigned int)ua | ((unsigned int)ub << 16);
}

// ---- w1 [d][e] fp32  ->  w1t [e][d] bf16 ----
__global__ void transpose_cvt(const float* __restrict__ w1, unsigned short* __restrict__ w1t) {
    __shared__ float tile[32][33];
    const int tx = threadIdx.x, ty = threadIdx.y;
    const int e = blockIdx.x * 32 + tx;
    const int d = blockIdx.y * 32 + ty;
    tile[ty][tx] = w1[d * 1024 + e];
    __syncthreads();
    const int eo = blockIdx.x * 32 + ty;
    const int dq = blockIdx.y * 32 + tx;
    __hip_bfloat16 h = __float2bfloat16(tile[tx][ty]);
    unsigned short us;
    __builtin_memcpy(&us, &h, 2);
    w1t[eo * 1024 + dq] = us;
}

// ---- qq[b][e] = b1[e] + b2[e] + sum_d dec[b][d]*w2[d][e]  (fp32) ----
__global__ __launch_bounds__(256) void qq_kern(const float* __restrict__ dec,
                                               const float* __restrict__ w2,
                                               const float* __restrict__ b1,
                                               const float* __restrict__ b2,
                                               float* __restrict__ qq) {
    const int b = blockIdx.y;
    const int e = blockIdx.x * 256 + threadIdx.x;
    const float* db = dec + b * 1024;
    float acc = b1[e] + b2[e];
#pragma unroll 4
    for (int d = 0; d < 1024; d++)
        acc = fmaf(db[d], w2[d * 1024 + e], acc);
    qq[b * 1024 + e] = acc;
}

// ---- big fused GEMM: scores[m] += sum_{n in tile} tanh(enc@w1 + qq)[m][n] * v[n] ----
__global__ __launch_bounds__(256) void score_gemm(const float* __restrict__ enc,
                                                  const unsigned short* __restrict__ w1t,
                                                  const float* __restrict__ qq,
                                                  const float* __restrict__ vvec,
                                                  float* __restrict__ scores) {
    __shared__ __align__(16) unsigned short As[128 * LDSP];
    __shared__ __align__(16) unsigned short Bs[128 * LDSP];

    // XCD swizzle: the 8 n-tiles of one m-strip land on the same XCD, adjacent in dispatch.
    const int g = blockIdx.x;                 // 0..4095
    const int mtile = (g & 7) * 64 + (g >> 6);  // 0..511
    const int ntile = (g >> 3) & 7;             // 0..7
    const int m0 = mtile * 128;
    const int n0 = ntile * 128;
    const int b = m0 >> 11;   // 2048 rows per batch; 128 | 2048 so no tile crosses batches

    const int tid = threadIdx.x;
    const int wid = tid >> 6;
    const int lane = tid & 63;
    const int wm = wid >> 1, wn = wid & 1;      // 2x2 wave grid, each wave 64x64
    const int quad = lane >> 4, lc = lane & 15;

    const int srow = tid >> 1;            // 0..127 (staging row)
    const int shalf = (tid & 1) * 16;     // k-offset in elements

    f32x4 acc[4][4];
#pragma unroll
    for (int mi = 0; mi < 4; mi++)
#pragma unroll
        for (int ni = 0; ni < 4; ni++)
            acc[mi][ni] = (f32x4){0.f, 0.f, 0.f, 0.f};

    const float* aptr = enc + (size_t)(m0 + srow) * 1024 + shalf;
    const unsigned short* bptr = w1t + (size_t)(n0 + srow) * 1024 + shalf;

    for (int k0 = 0; k0 < KDIM; k0 += 32) {
        // stage A: 16 fp32 -> 16 bf16 per thread
        const float4* a4 = reinterpret_cast<const float4*>(aptr + k0);
        float4 f0 = a4[0], f1 = a4[1], f2 = a4[2], f3 = a4[3];
        // stage B: already bf16, 32B per thread
        const uint4* b4 = reinterpret_cast<const uint4*>(bptr + k0);
        uint4 bw0 = b4[0], bw1 = b4[1];

        uint4 aw0, aw1;
        aw0.x = pk2(f0.x, f0.y); aw0.y = pk2(f0.z, f0.w);
        aw0.z = pk2(f1.x, f1.y); aw0.w = pk2(f1.z, f1.w);
        aw1.x = pk2(f2.x, f2.y); aw1.y = pk2(f2.z, f2.w);
        aw1.z = pk2(f3.x, f3.y); aw1.w = pk2(f3.z, f3.w);

        __syncthreads();   // previous iteration's LDS reads must complete
        *reinterpret_cast<uint4*>(&As[srow * LDSP + shalf]) = aw0;
        *reinterpret_cast<uint4*>(&As[srow * LDSP + shalf + 8]) = aw1;
        *reinterpret_cast<uint4*>(&Bs[srow * LDSP + shalf]) = bw0;
        *reinterpret_cast<uint4*>(&Bs[srow * LDSP + shalf + 8]) = bw1;
        __syncthreads();

        short8 af[4], bf[4];
#pragma unroll
        for (int i = 0; i < 4; i++) {
            af[i] = *reinterpret_cast<const short8*>(&As[(wm * 64 + i * 16 + lc) * LDSP + quad * 8]);
            bf[i] = *reinterpret_cast<const short8*>(&Bs[(wn * 64 + i * 16 + lc) * LDSP + quad * 8]);
        }
#pragma unroll
        for (int mi = 0; mi < 4; mi++)
#pragma unroll
            for (int ni = 0; ni < 4; ni++)
                acc[mi][ni] = __builtin_amdgcn_mfma_f32_16x16x32_bf16(af[mi], bf[ni], acc[mi][ni], 0, 0, 0);
    }

    // epilogue: tanh(C + qq[b][n]) * v[n], row-reduce, atomic into scores
    const float* qqb = qq + b * 1024;
    const int nb = n0 + wn * 64 + lc;
    float qn[4], vn[4];
#pragma unroll
    for (int ni = 0; ni < 4; ni++) {
        qn[ni] = qqb[nb + ni * 16];
        vn[ni] = vvec[nb + ni * 16];
    }

    float red[16];
#pragma unroll
    for (int mi = 0; mi < 4; mi++) {
#pragma unroll
        for (int r = 0; r < 4; r++) {
            float ssum = 0.f;
#pragma unroll
            for (int ni = 0; ni < 4; ni++) {
                float x = acc[mi][ni][r] + qn[ni];
                // overflow-safe tanh: 1 - 2/(e^{2x}+1); exp->inf gives +1, exp->0 gives -1
                float e = __expf(2.0f * x);
                float th = 1.0f - 2.0f / (e + 1.0f);
                ssum = fmaf(th, vn[ni], ssum);
            }
            // butterfly across the 16 lanes of this quad (same rows, 16 columns)
            float t = ssum;
            t += __shfl_xor(t, 1);
            t += __shfl_xor(t, 2);
            t += __shfl_xor(t, 4);
            t += __shfl_xor(t, 8);
            red[mi * 4 + r] = t;
        }
    }
    // lane lc handles (mi,r) = (lc>>2, lc&3); all lanes hold all 16 sums
    float myv = red[0];
#pragma unroll
    for (int i = 1; i < 16; i++)
        if (lc == i) myv = red[i];
    atomicAdd(scores + m0 + wm * 64 + (lc >> 2) * 16 + quad * 4 + (lc & 3), myv);
}

// ---- softmax over s (2048) per batch ----
__global__ __launch_bounds__(256) void softmax_kern(const float* __restrict__ scores,
                                                    float* __restrict__ attn) {
    const int b = blockIdx.x;
    const int tid = threadIdx.x;
    const int wid = tid >> 6, lane = tid & 63;
    const float* s = scores + b * 2048;
    float x[8];
    float m = -1e30f;
#pragma unroll
    for (int i = 0; i < 8; i++) {
        x[i] = s[tid + i * 256];
        m = fmaxf(m, x[i]);
    }
    for (int off = 1; off < 64; off <<= 1) m = fmaxf(m, __shfl_xor(m, off));
    __shared__ float redm[4];
    if (lane == 0) redm[wid] = m;
    __syncthreads();
    m = fmaxf(fmaxf(redm[0], redm[1]), fmaxf(redm[2], redm[3]));
    float sum = 0.f;
#pragma unroll
    for (int i = 0; i < 8; i++) {
        x[i] = __expf(x[i] - m);
        sum += x[i];
    }
    for (int off = 1; off < 64; off <<= 1) sum += __shfl_xor(sum, off);
    __shared__ float reds[4];
    if (lane == 0) reds[wid] = sum;
    __syncthreads();
    sum = reds[0] + reds[1] + reds[2] + reds[3];
    const float inv = 1.0f / sum;
#pragma unroll
    for (int i = 0; i < 8; i++) attn[b * 2048 + tid + i * 256] = x[i] * inv;
}

// ---- context[b][e] = sum_s attn[b][s] * enc[b][s][e] ----
__global__ __launch_bounds__(256) void ctx_kern(const float* __restrict__ attn,
                                                const float* __restrict__ enc,
                                                float* __restrict__ out) {
    const int b = blockIdx.y;     // 32
    const int sc = blockIdx.x;    // 16 chunks x 128 s
    const int tid = threadIdx.x;  // 256 threads x float4 = 1024 e
    const float* ab = attn + b * 2048 + sc * 128;
    const float* eb = enc + ((size_t)b * 2048 + sc * 128) * 1024 + tid * 4;
    float4 acc = {0.f, 0.f, 0.f, 0.f};
#pragma unroll 4
    for (int s = 0; s < 128; s++) {
        float w = ab[s];
        float4 ev = *reinterpret_cast<const float4*>(eb + (size_t)s * 1024);
        acc.x = fmaf(w, ev.x, acc.x);
        acc.y = fmaf(w, ev.y, acc.y);
        acc.z = fmaf(w, ev.z, acc.z);
        acc.w = fmaf(w, ev.w, acc.w);
    }
    float* o = out + b * 1024 + tid * 4;
    atomicAdd(o + 0, acc.x);
    atomicAdd(o + 1, acc.y);
    atomicAdd(o + 2, acc.z);
    atomicAdd(o + 3, acc.w);
}

extern "C" void kernel_launch(void* const* d_in, const int* in_sizes, int n_in,
                              void* d_out, int out_size, void* d_ws, size_t ws_size,
                              hipStream_t stream) {
    const float* enc = (const float*)d_in[0];  // 32*2048*1024
    const float* dec = (const float*)d_in[1];  // 32*1*1024
    const float* w1  = (const float*)d_in[2];  // 1024*1024
    const float* b1  = (const float*)d_in[3];  // 1024
    const float* w2  = (const float*)d_in[4];  // 1024*1024
    const float* b2  = (const float*)d_in[5];  // 1024
    const float* v   = (const float*)d_in[6];  // 1024
    // d_in[7] = bv, softmax-invariant, unused
    float* out = (float*)d_out;                // 32*1024

    char* ws = (char*)d_ws;
    unsigned short* w1t = (unsigned short*)ws;                 // 2 MB
    float* qq     = (float*)(ws + (2u << 20));                 // 128 KB
    float* scores = (float*)(ws + (2u << 20) + (128u << 10));  // 256 KB
    float* attn   = scores + M_TOTAL;                          // 256 KB

    hipMemsetAsync(scores, 0, M_TOTAL * sizeof(float), stream);
    hipMemsetAsync(out, 0, 32 * 1024 * sizeof(float), stream);

    transpose_cvt<<<dim3(32, 32), dim3(32, 32), 0, stream>>>(w1, w1t);
    qq_kern<<<dim3(4, 32), 256, 0, stream>>>(dec, w2, b1, b2, qq);
    score_gemm<<<4096, 256, 0, stream>>>(enc, w1t, qq, v, scores);
    softmax_kern<<<32, 256, 0, stream>>>(scores, attn);
    ctx_kern<<<dim3(16, 32), 256, 0, stream>>>(attn, enc, out);
}

// Round 2
// 736.690 us; speedup vs baseline: 1.0424x; 1.0424x over previous
//
#include <hip/hip_runtime.h>
#include <hip/hip_bf16.h>

// Bahdanau additive attention, MI355X. B=32, S=2048, E=D=1024. M = B*S = 65536.
// scores[m] = v . tanh(enc[m,:] @ w1 + qq[b]),  qq[b] = dec[b] @ w2 + b2 + b1
// (bv dropped: softmax-invariant). attn = softmax_s(scores); context[b] = attn[b,:] @ enc[b,:,:]
//
// LDS layout for the GEMM: rows of 32 bf16 (64B) = 4 chunks of 16B.
// Swizzle: chunk_stored = chunk ^ ((row>>1)&3). Conflict-free for both the
// uint4 staging stores and the ds_read_b128 fragment reads (every 8-lane
// phase covers all 32 banks exactly once).
// w1 is pre-packed in global memory in EXACTLY this swizzled tile order, so
// B-staging is pure global_load_lds width-16 DMA (no VGPR round-trip).

typedef __attribute__((ext_vector_type(8))) short short8;   // 8 bf16 (4 VGPRs)
typedef __attribute__((ext_vector_type(4))) float f32x4;    // MFMA acc

#define M_TOTAL 65536
#define KDIM    1024

// pack two fp32 -> two bf16 (round-half-up) in one dword: 2 adds + 1 v_perm
static __device__ inline unsigned int pk2h(float a, float b) {
    unsigned int ua = __builtin_bit_cast(unsigned int, a) + 0x8000u;
    unsigned int ub = __builtin_bit_cast(unsigned int, b) + 0x8000u;
    // result bytes {0,1} = ua bytes {2,3}; bytes {2,3} = ub bytes {2,3}
    return __builtin_amdgcn_perm(ub, ua, 0x07060302u);
}

static __device__ inline void async_copy16(const void* g, void* l) {
    __builtin_amdgcn_global_load_lds(
        (const __attribute__((address_space(1))) unsigned int*)g,
        (__attribute__((address_space(3))) unsigned int*)l, 16, 0, 0);
}

// ---- w1 [d][e] fp32 -> w1p: bf16, tiled+swizzled: for e-tile nt (8), k-chunk kc (32):
//      w1p[(nt*32+kc)*4096 + r*32 + (c^((r>>1)&3))*8 + j] = bf16(w1[kc*32+c*8+j][nt*128+r])
__global__ void pack_w1(const float* __restrict__ w1, unsigned short* __restrict__ w1p) {
    __shared__ float tile[32][33];
    const int tx = threadIdx.x, ty = threadIdx.y;
    tile[ty][tx] = w1[(blockIdx.y * 32 + ty) * 1024 + blockIdx.x * 32 + tx];
    __syncthreads();
    const int eo = blockIdx.x * 32 + ty;   // output row (n-dim)
    const int dq = blockIdx.y * 32 + tx;   // k-dim
    const float f = tile[tx][ty];          // = w1[dq][eo]
    const unsigned int u = __builtin_bit_cast(unsigned int, f) + 0x8000u;
    const unsigned short us = (unsigned short)(u >> 16);
    const int nt = eo >> 7, r = eo & 127;
    const int kc = dq >> 5, c = (dq >> 3) & 3, j = dq & 7;
    const int cs = c ^ ((r >> 1) & 3);
    w1p[((nt * 32 + kc) << 12) + (r << 5) + (cs << 3) + j] = us;
}

// ---- qq[b][e] += partial of b1+b2 + dec[b]@w2, split-k x4 ----
__global__ __launch_bounds__(256) void qq_kern(const float* __restrict__ dec,
                                               const float* __restrict__ w2,
                                               const float* __restrict__ b1,
                                               const float* __restrict__ b2,
                                               float* __restrict__ qq) {
    const int b = blockIdx.y;
    const int e = blockIdx.x * 256 + threadIdx.x;
    const int d0 = blockIdx.z * 256;
    const float* db = dec + b * 1024;
    float acc = (blockIdx.z == 0) ? (b1[e] + b2[e]) : 0.f;
#pragma unroll 8
    for (int d = d0; d < d0 + 256; d++)
        acc = fmaf(db[d], w2[d * 1024 + e], acc);
    atomicAdd(&qq[b * 1024 + e], acc);
}

// ---- fused GEMM: scores[m] += sum_n tanh(enc@w1 + qq)[m][n] * v[n] ----
__global__ __launch_bounds__(256) void score_gemm(const float* __restrict__ enc,
                                                  const unsigned short* __restrict__ w1p,
                                                  const float* __restrict__ qq,
                                                  const float* __restrict__ vvec,
                                                  float* __restrict__ scores) {
    __shared__ __align__(16) unsigned short As[128 * 32];
    __shared__ __align__(16) unsigned short Bs[128 * 32];

    // XCD swizzle: 8 n-tiles of one m-strip adjacent in dispatch.
    const int g = blockIdx.x;                   // 0..4095
    const int mtile = (g & 7) * 64 + (g >> 6);  // 0..511
    const int ntile = (g >> 3) & 7;             // 0..7
    const int m0 = mtile * 128;
    const int b = m0 >> 11;

    const int tid = threadIdx.x;
    const int wid = tid >> 6;
    const int lane = tid & 63;
    const int wm = wid >> 1, wn = wid & 1;      // 2x2 wave grid, 64x64 each
    const int quad = lane >> 4, lc = lane & 15;

    // A staging: thread -> (row, 16-float half-row)
    const int srow = tid >> 1;
    const int shalf = (tid & 1) * 16;
    const int scb = (tid & 1) * 2;              // chunk base (0 or 2)
    const int ssw = (srow >> 1) & 3;            // store swizzle
    const int aw0_off = (srow << 5) + (((scb    ) ^ ssw) << 3);
    const int aw1_off = (srow << 5) + (((scb + 1) ^ ssw) << 3);
    // fragment read swizzle: rows i*16+lc -> (row>>1)&3 == (lc>>1)&3
    const int fsw = (lc >> 1) & 3;
    const int frd_chunk = ((quad ^ fsw) << 3);

    f32x4 acc[4][4];
#pragma unroll
    for (int mi = 0; mi < 4; mi++)
#pragma unroll
        for (int ni = 0; ni < 4; ni++)
            acc[mi][ni] = (f32x4){0.f, 0.f, 0.f, 0.f};

    const float* aptr = enc + (size_t)(m0 + srow) * 1024 + shalf;
    // B DMA: wave wid covers tile rows wid*32..wid*32+31, 2 instrs x 1KB, linear
    const unsigned short* bbase = w1p + ((size_t)ntile << 17) + (wid << 10) + (lane << 3);
    unsigned short* bdst0 = &Bs[(wid << 10)];
    unsigned short* bdst1 = &Bs[(wid << 10) + 512];

    // software-pipelined A loads: prefetch next k-iter before the barrier
    float4 fA[4];
    {
        const float4* a4 = reinterpret_cast<const float4*>(aptr);
#pragma unroll
        for (int i = 0; i < 4; i++) fA[i] = a4[i];
    }

    for (int k0 = 0; k0 < KDIM; k0 += 32) {
        float4 gA[4];
        {
            const int k1 = (k0 + 32 < KDIM) ? k0 + 32 : k0;
            const float4* a4 = reinterpret_cast<const float4*>(aptr + k1);
#pragma unroll
            for (int i = 0; i < 4; i++) gA[i] = a4[i];
        }

        __syncthreads();   // prior iteration's LDS reads done

        // B: pure DMA into swizzled layout (w1p pre-packed in this order)
        {
            const unsigned short* bsrc = bbase + ((size_t)(k0 >> 5) << 12);
            async_copy16(bsrc, bdst0);
            async_copy16(bsrc + 512, bdst1);
        }
        // A: pack fp32 -> bf16 (3 VALU per 2 floats) and store swizzled
        uint4 aw0, aw1;
        aw0.x = pk2h(fA[0].x, fA[0].y); aw0.y = pk2h(fA[0].z, fA[0].w);
        aw0.z = pk2h(fA[1].x, fA[1].y); aw0.w = pk2h(fA[1].z, fA[1].w);
        aw1.x = pk2h(fA[2].x, fA[2].y); aw1.y = pk2h(fA[2].z, fA[2].w);
        aw1.z = pk2h(fA[3].x, fA[3].y); aw1.w = pk2h(fA[3].z, fA[3].w);
        *reinterpret_cast<uint4*>(&As[aw0_off]) = aw0;
        *reinterpret_cast<uint4*>(&As[aw1_off]) = aw1;

        __syncthreads();   // drains DMA (vmcnt) + ds_write (lgkmcnt)

        short8 af[4], bf[4];
#pragma unroll
        for (int i = 0; i < 4; i++) {
            af[i] = *reinterpret_cast<const short8*>(&As[((wm * 64 + i * 16 + lc) << 5) + frd_chunk]);
            bf[i] = *reinterpret_cast<const short8*>(&Bs[((wn * 64 + i * 16 + lc) << 5) + frd_chunk]);
        }
#pragma unroll
        for (int mi = 0; mi < 4; mi++)
#pragma unroll
            for (int ni = 0; ni < 4; ni++)
                acc[mi][ni] = __builtin_amdgcn_mfma_f32_16x16x32_bf16(af[mi], bf[ni], acc[mi][ni], 0, 0, 0);

#pragma unroll
        for (int i = 0; i < 4; i++) fA[i] = gA[i];
    }

    // epilogue: tanh(C + qq[b][n]) * v[n], reduce over n, atomic into scores
    const float* qqb = qq + b * 1024;
    const int nb = ntile * 128 + wn * 64 + lc;
    float qn[4], vn[4];
#pragma unroll
    for (int ni = 0; ni < 4; ni++) {
        qn[ni] = qqb[nb + ni * 16];
        vn[ni] = vvec[nb + ni * 16];
    }

    float red[16];
#pragma unroll
    for (int mi = 0; mi < 4; mi++) {
#pragma unroll
        for (int r = 0; r < 4; r++) {
            float ssum = 0.f;
#pragma unroll
            for (int ni = 0; ni < 4; ni++) {
                float x = acc[mi][ni][r] + qn[ni];
                float e = __expf(2.0f * x);          // overflow-safe tanh
                float th = 1.0f - 2.0f / (e + 1.0f);
                ssum = fmaf(th, vn[ni], ssum);
            }
            float t = ssum;                           // quad-wide (16 lanes) butterfly
            t += __shfl_xor(t, 1);
            t += __shfl_xor(t, 2);
            t += __shfl_xor(t, 4);
            t += __shfl_xor(t, 8);
            red[mi * 4 + r] = t;
        }
    }
    float myv = red[0];
#pragma unroll
    for (int i = 1; i < 16; i++)
        if (lc == i) myv = red[i];
    atomicAdd(scores + m0 + wm * 64 + (lc >> 2) * 16 + quad * 4 + (lc & 3), myv);
}

// ---- softmax over s (2048) per batch ----
__global__ __launch_bounds__(256) void softmax_kern(const float* __restrict__ scores,
                                                    float* __restrict__ attn) {
    const int b = blockIdx.x;
    const int tid = threadIdx.x;
    const int wid = tid >> 6, lane = tid & 63;
    const float* s = scores + b * 2048;
    float x[8];
    float m = -1e30f;
#pragma unroll
    for (int i = 0; i < 8; i++) {
        x[i] = s[tid + i * 256];
        m = fmaxf(m, x[i]);
    }
    for (int off = 1; off < 64; off <<= 1) m = fmaxf(m, __shfl_xor(m, off));
    __shared__ float redm[4];
    if (lane == 0) redm[wid] = m;
    __syncthreads();
    m = fmaxf(fmaxf(redm[0], redm[1]), fmaxf(redm[2], redm[3]));
    float sum = 0.f;
#pragma unroll
    for (int i = 0; i < 8; i++) {
        x[i] = __expf(x[i] - m);
        sum += x[i];
    }
    for (int off = 1; off < 64; off <<= 1) sum += __shfl_xor(sum, off);
    __shared__ float reds[4];
    if (lane == 0) reds[wid] = sum;
    __syncthreads();
    sum = reds[0] + reds[1] + reds[2] + reds[3];
    const float inv = 1.0f / sum;
#pragma unroll
    for (int i = 0; i < 8; i++) attn[b * 2048 + tid + i * 256] = x[i] * inv;
}

// ---- context[b][e] = sum_s attn[b][s] * enc[b][s][e] ----
// 1024 blocks, unroll 16: ~4KB of loads in flight per CU (latency-bound fix)
__global__ __launch_bounds__(256) void ctx_kern(const float* __restrict__ attn,
                                                const float* __restrict__ enc,
                                                float* __restrict__ out) {
    const int b = blockIdx.y;     // 32
    const int sc = blockIdx.x;    // 32 chunks x 64 s
    const int tid = threadIdx.x;  // 256 threads x float4 = 1024 e
    const float* ab = attn + b * 2048 + sc * 64;
    const float* eb = enc + ((size_t)b * 2048 + sc * 64) * 1024 + tid * 4;
    float4 acc = {0.f, 0.f, 0.f, 0.f};
#pragma unroll 16
    for (int s = 0; s < 64; s++) {
        float w = ab[s];
        float4 ev = *reinterpret_cast<const float4*>(eb + (size_t)s * 1024);
        acc.x = fmaf(w, ev.x, acc.x);
        acc.y = fmaf(w, ev.y, acc.y);
        acc.z = fmaf(w, ev.z, acc.z);
        acc.w = fmaf(w, ev.w, acc.w);
    }
    float* o = out + b * 1024 + tid * 4;
    atomicAdd(o + 0, acc.x);
    atomicAdd(o + 1, acc.y);
    atomicAdd(o + 2, acc.z);
    atomicAdd(o + 3, acc.w);
}

extern "C" void kernel_launch(void* const* d_in, const int* in_sizes, int n_in,
                              void* d_out, int out_size, void* d_ws, size_t ws_size,
                              hipStream_t stream) {
    const float* enc = (const float*)d_in[0];  // 32*2048*1024
    const float* dec = (const float*)d_in[1];  // 32*1*1024
    const float* w1  = (const float*)d_in[2];  // 1024*1024
    const float* b1  = (const float*)d_in[3];  // 1024
    const float* w2  = (const float*)d_in[4];  // 1024*1024
    const float* b2  = (const float*)d_in[5];  // 1024
    const float* v   = (const float*)d_in[6];  // 1024
    // d_in[7] = bv, softmax-invariant, unused
    float* out = (float*)d_out;                // 32*1024

    char* ws = (char*)d_ws;
    unsigned short* w1p = (unsigned short*)ws;                 // 2 MB
    float* qq     = (float*)(ws + (2u << 20));                 // 128 KB
    float* scores = (float*)(ws + (2u << 20) + (128u << 10));  // 256 KB
    float* attn   = scores + M_TOTAL;                          // 256 KB

    // zero qq + scores in one memset (they're adjacent)
    hipMemsetAsync(qq, 0, (128u << 10) + M_TOTAL * sizeof(float), stream);
    hipMemsetAsync(out, 0, 32 * 1024 * sizeof(float), stream);

    pack_w1<<<dim3(32, 32), dim3(32, 32), 0, stream>>>(w1, w1p);
    qq_kern<<<dim3(4, 32, 4), 256, 0, stream>>>(dec, w2, b1, b2, qq);
    score_gemm<<<4096, 256, 0, stream>>>(enc, w1p, qq, v, scores);
    softmax_kern<<<32, 256, 0, stream>>>(scores, attn);
    ctx_kern<<<dim3(32, 32), 256, 0, stream>>>(attn, enc, out);
}

// Round 3
// 669.034 us; speedup vs baseline: 1.1478x; 1.1011x over previous
//
#include <hip/hip_runtime.h>
#include <hip/hip_bf16.h>

// Bahdanau additive attention, MI355X. B=32, S=2048, E=D=1024. M = B*S = 65536.
// scores[m] = v . tanh(enc[m,:] @ w1 + qq[b]),  qq[b] = dec[b] @ w2 + b2 + b1
// (bv dropped: softmax-invariant). attn = softmax_s(scores); context[b] = attn[b,:] @ enc[b,:,:]
//
// LDS image layout (per 128x32 bf16 tile): row-major rows of 64B, each row =
// 4 chunks of 16B, chunk stored at position chunk ^ ((row>>1)&3). Verified
// conflict-free (round 2: SQ_LDS_BANK_CONFLICT == 0).
// BOTH operands are pre-packed in global memory in exactly this image order
// (enc via cvt_enc each launch, w1 via pack_w1), so GEMM staging is pure
// global_load_lds width-16 DMA — the m97 structure (no VGPR round-trip,
// no conversion VALU, no software prefetch).

typedef __attribute__((ext_vector_type(8))) short short8;   // 8 bf16 (4 VGPRs)
typedef __attribute__((ext_vector_type(4))) float f32x4;    // MFMA acc

#define M_TOTAL 65536
#define KDIM    1024

// pack two fp32 -> two bf16 (round-half-up) in one dword: 2 adds + 1 v_perm
static __device__ inline unsigned int pk2h(float a, float b) {
    unsigned int ua = __builtin_bit_cast(unsigned int, a) + 0x8000u;
    unsigned int ub = __builtin_bit_cast(unsigned int, b) + 0x8000u;
    return __builtin_amdgcn_perm(ub, ua, 0x07060302u);
}

static __device__ inline void async_copy16(const void* g, void* l) {
    __builtin_amdgcn_global_load_lds(
        (const __attribute__((address_space(1))) unsigned int*)g,
        (__attribute__((address_space(3))) unsigned int*)l, 16, 0, 0);
}

// ---- w1 [d][e] fp32 -> w1p bf16 tiled+swizzled LDS-image order ----
__global__ void pack_w1(const float* __restrict__ w1, unsigned short* __restrict__ w1p) {
    __shared__ float tile[32][33];
    const int tx = threadIdx.x, ty = threadIdx.y;
    tile[ty][tx] = w1[(blockIdx.y * 32 + ty) * 1024 + blockIdx.x * 32 + tx];
    __syncthreads();
    const int eo = blockIdx.x * 32 + ty;   // n-dim
    const int dq = blockIdx.y * 32 + tx;   // k-dim
    const unsigned int u = __builtin_bit_cast(unsigned int, tile[tx][ty]) + 0x8000u;
    const unsigned short us = (unsigned short)(u >> 16);
    const int nt = eo >> 7, r = eo & 127;
    const int kc = dq >> 5, c = (dq >> 3) & 3, j = dq & 7;
    const int cs = c ^ ((r >> 1) & 3);
    w1p[((nt * 32 + kc) << 12) + (r << 5) + (cs << 3) + j] = us;
}

// ---- enc fp32 -> encp bf16, tiled+swizzled LDS-image order (per launch) ----
// block g = mtile*32 + kc: covers rows mtile*128..+128, cols kc*32..+32
__global__ __launch_bounds__(256) void cvt_enc(const float* __restrict__ enc,
                                               unsigned short* __restrict__ encp) {
    const int g = blockIdx.x;
    const int kc = g & 31, mtile = g >> 5;
    const int tid = threadIdx.x;
    const int srow = tid >> 1, half = tid & 1;
    const float4* src = reinterpret_cast<const float4*>(
        enc + ((size_t)(mtile * 128 + srow)) * 1024 + kc * 32 + half * 16);
    float4 f0 = src[0], f1 = src[1], f2 = src[2], f3 = src[3];
    uint4 w0, w1v;
    w0.x = pk2h(f0.x, f0.y); w0.y = pk2h(f0.z, f0.w);
    w0.z = pk2h(f1.x, f1.y); w0.w = pk2h(f1.z, f1.w);
    w1v.x = pk2h(f2.x, f2.y); w1v.y = pk2h(f2.z, f2.w);
    w1v.z = pk2h(f3.x, f3.y); w1v.w = pk2h(f3.z, f3.w);
    const int ssw = (srow >> 1) & 3;
    const int c0 = (half * 2) ^ ssw, c1 = (half * 2 + 1) ^ ssw;
    unsigned short* dst = encp + ((size_t)g << 12) + (srow << 5);
    *reinterpret_cast<uint4*>(dst + (c0 << 3)) = w0;
    *reinterpret_cast<uint4*>(dst + (c1 << 3)) = w1v;
}

// ---- qq[b][e] += partial of b1+b2 + dec[b]@w2, split-k x4 ----
__global__ __launch_bounds__(256) void qq_kern(const float* __restrict__ dec,
                                               const float* __restrict__ w2,
                                               const float* __restrict__ b1,
                                               const float* __restrict__ b2,
                                               float* __restrict__ qq) {
    const int b = blockIdx.y;
    const int e = blockIdx.x * 256 + threadIdx.x;
    const int d0 = blockIdx.z * 256;
    const float* db = dec + b * 1024;
    float acc = (blockIdx.z == 0) ? (b1[e] + b2[e]) : 0.f;
#pragma unroll 8
    for (int d = d0; d < d0 + 256; d++)
        acc = fmaf(db[d], w2[d * 1024 + e], acc);
    atomicAdd(&qq[b * 1024 + e], acc);
}

// ---- shared epilogue: tanh(C + qq)*v, quad butterfly, atomic into scores ----
static __device__ inline void score_epilogue(f32x4 acc[4][4], const float* qqb,
                                             const float* vvec, float* scores,
                                             int m0, int n0, int wm, int wn,
                                             int quad, int lc) {
    const int nb = n0 + wn * 64 + lc;
    float qn[4], vn[4];
#pragma unroll
    for (int ni = 0; ni < 4; ni++) {
        qn[ni] = qqb[nb + ni * 16];
        vn[ni] = vvec[nb + ni * 16];
    }
    float red[16];
#pragma unroll
    for (int mi = 0; mi < 4; mi++) {
#pragma unroll
        for (int r = 0; r < 4; r++) {
            float ssum = 0.f;
#pragma unroll
            for (int ni = 0; ni < 4; ni++) {
                float x = acc[mi][ni][r] + qn[ni];
                float e = __expf(2.0f * x);          // overflow-safe tanh
                float th = 1.0f - 2.0f / (e + 1.0f);
                ssum = fmaf(th, vn[ni], ssum);
            }
            float t = ssum;
            t += __shfl_xor(t, 1);
            t += __shfl_xor(t, 2);
            t += __shfl_xor(t, 4);
            t += __shfl_xor(t, 8);
            red[mi * 4 + r] = t;
        }
    }
    float myv = red[0];
#pragma unroll
    for (int i = 1; i < 16; i++)
        if (lc == i) myv = red[i];
    atomicAdd(scores + m0 + wm * 64 + (lc >> 2) * 16 + quad * 4 + (lc & 3), myv);
}

// ---- fused GEMM, pure-DMA staging (m97 structure) ----
__global__ __launch_bounds__(256) void score_gemm_dma(const unsigned short* __restrict__ encp,
                                                      const unsigned short* __restrict__ w1p,
                                                      const float* __restrict__ qq,
                                                      const float* __restrict__ vvec,
                                                      float* __restrict__ scores) {
    __shared__ __align__(16) unsigned short As[128 * 32];
    __shared__ __align__(16) unsigned short Bs[128 * 32];

    const int g = blockIdx.x;                   // 0..4095, XCD swizzle
    const int mtile = (g & 7) * 64 + (g >> 6);  // 0..511
    const int ntile = (g >> 3) & 7;             // 0..7
    const int m0 = mtile * 128;
    const int b = m0 >> 11;

    const int tid = threadIdx.x;
    const int wid = tid >> 6;
    const int lane = tid & 63;
    const int wm = wid >> 1, wn = wid & 1;
    const int quad = lane >> 4, lc = lane & 15;
    const int frd_chunk = ((quad ^ ((lc >> 1) & 3)) << 3);

    f32x4 acc[4][4];
#pragma unroll
    for (int mi = 0; mi < 4; mi++)
#pragma unroll
        for (int ni = 0; ni < 4; ni++)
            acc[mi][ni] = (f32x4){0.f, 0.f, 0.f, 0.f};

    // DMA sources: per-wave 2KB of each operand tile, linear image copy
    const unsigned short* abase = encp + ((size_t)mtile << 17) + (wid << 10) + (lane << 3);
    const unsigned short* bbase = w1p + ((size_t)ntile << 17) + (wid << 10) + (lane << 3);
    unsigned short* adst = &As[wid << 10];
    unsigned short* bdst = &Bs[wid << 10];

    for (int k0 = 0; k0 < KDIM; k0 += 32) {
        __syncthreads();   // prior iteration's LDS reads done
        const size_t koff = (size_t)(k0 >> 5) << 12;
        const unsigned short* asrc = abase + koff;
        const unsigned short* bsrc = bbase + koff;
        async_copy16(asrc, adst);
        async_copy16(asrc + 512, adst + 512);
        async_copy16(bsrc, bdst);
        async_copy16(bsrc + 512, bdst + 512);
        __syncthreads();   // vmcnt(0): DMA complete

        short8 af[4], bf[4];
#pragma unroll
        for (int i = 0; i < 4; i++) {
            af[i] = *reinterpret_cast<const short8*>(&As[((wm * 64 + i * 16 + lc) << 5) + frd_chunk]);
            bf[i] = *reinterpret_cast<const short8*>(&Bs[((wn * 64 + i * 16 + lc) << 5) + frd_chunk]);
        }
#pragma unroll
        for (int mi = 0; mi < 4; mi++)
#pragma unroll
            for (int ni = 0; ni < 4; ni++)
                acc[mi][ni] = __builtin_amdgcn_mfma_f32_16x16x32_bf16(af[mi], bf[ni], acc[mi][ni], 0, 0, 0);
    }

    score_epilogue(acc, qq + b * 1024, vvec, scores, m0, ntile * 128, wm, wn, quad, lc);
}

// ---- fallback GEMM (ws too small): inline A convert, B DMA, no prefetch ----
__global__ __launch_bounds__(256) void score_gemm_fb(const float* __restrict__ enc,
                                                     const unsigned short* __restrict__ w1p,
                                                     const float* __restrict__ qq,
                                                     const float* __restrict__ vvec,
                                                     float* __restrict__ scores) {
    __shared__ __align__(16) unsigned short As[128 * 32];
    __shared__ __align__(16) unsigned short Bs[128 * 32];

    const int g = blockIdx.x;
    const int mtile = (g & 7) * 64 + (g >> 6);
    const int ntile = (g >> 3) & 7;
    const int m0 = mtile * 128;
    const int b = m0 >> 11;

    const int tid = threadIdx.x;
    const int wid = tid >> 6;
    const int lane = tid & 63;
    const int wm = wid >> 1, wn = wid & 1;
    const int quad = lane >> 4, lc = lane & 15;

    const int srow = tid >> 1;
    const int shalf = (tid & 1) * 16;
    const int scb = (tid & 1) * 2;
    const int ssw = (srow >> 1) & 3;
    const int aw0_off = (srow << 5) + (((scb) ^ ssw) << 3);
    const int aw1_off = (srow << 5) + (((scb + 1) ^ ssw) << 3);
    const int frd_chunk = ((quad ^ ((lc >> 1) & 3)) << 3);

    f32x4 acc[4][4];
#pragma unroll
    for (int mi = 0; mi < 4; mi++)
#pragma unroll
        for (int ni = 0; ni < 4; ni++)
            acc[mi][ni] = (f32x4){0.f, 0.f, 0.f, 0.f};

    const float* aptr = enc + (size_t)(m0 + srow) * 1024 + shalf;
    const unsigned short* bbase = w1p + ((size_t)ntile << 17) + (wid << 10) + (lane << 3);
    unsigned short* bdst = &Bs[wid << 10];

    for (int k0 = 0; k0 < KDIM; k0 += 32) {
        const float4* a4 = reinterpret_cast<const float4*>(aptr + k0);
        float4 f0 = a4[0], f1 = a4[1], f2 = a4[2], f3 = a4[3];
        __syncthreads();
        const unsigned short* bsrc = bbase + ((size_t)(k0 >> 5) << 12);
        async_copy16(bsrc, bdst);
        async_copy16(bsrc + 512, bdst + 512);
        uint4 aw0, aw1;
        aw0.x = pk2h(f0.x, f0.y); aw0.y = pk2h(f0.z, f0.w);
        aw0.z = pk2h(f1.x, f1.y); aw0.w = pk2h(f1.z, f1.w);
        aw1.x = pk2h(f2.x, f2.y); aw1.y = pk2h(f2.z, f2.w);
        aw1.z = pk2h(f3.x, f3.y); aw1.w = pk2h(f3.z, f3.w);
        *reinterpret_cast<uint4*>(&As[aw0_off]) = aw0;
        *reinterpret_cast<uint4*>(&As[aw1_off]) = aw1;
        __syncthreads();

        short8 af[4], bf[4];
#pragma unroll
        for (int i = 0; i < 4; i++) {
            af[i] = *reinterpret_cast<const short8*>(&As[((wm * 64 + i * 16 + lc) << 5) + frd_chunk]);
            bf[i] = *reinterpret_cast<const short8*>(&Bs[((wn * 64 + i * 16 + lc) << 5) + frd_chunk]);
        }
#pragma unroll
        for (int mi = 0; mi < 4; mi++)
#pragma unroll
            for (int ni = 0; ni < 4; ni++)
                acc[mi][ni] = __builtin_amdgcn_mfma_f32_16x16x32_bf16(af[mi], bf[ni], acc[mi][ni], 0, 0, 0);
    }

    score_epilogue(acc, qq + b * 1024, vvec, scores, m0, ntile * 128, wm, wn, quad, lc);
}

// ---- softmax over s (2048) per batch ----
__global__ __launch_bounds__(256) void softmax_kern(const float* __restrict__ scores,
                                                    float* __restrict__ attn) {
    const int b = blockIdx.x;
    const int tid = threadIdx.x;
    const int wid = tid >> 6, lane = tid & 63;
    const float* s = scores + b * 2048;
    float x[8];
    float m = -1e30f;
#pragma unroll
    for (int i = 0; i < 8; i++) {
        x[i] = s[tid + i * 256];
        m = fmaxf(m, x[i]);
    }
    for (int off = 1; off < 64; off <<= 1) m = fmaxf(m, __shfl_xor(m, off));
    __shared__ float redm[4];
    if (lane == 0) redm[wid] = m;
    __syncthreads();
    m = fmaxf(fmaxf(redm[0], redm[1]), fmaxf(redm[2], redm[3]));
    float sum = 0.f;
#pragma unroll
    for (int i = 0; i < 8; i++) {
        x[i] = __expf(x[i] - m);
        sum += x[i];
    }
    for (int off = 1; off < 64; off <<= 1) sum += __shfl_xor(sum, off);
    __shared__ float reds[4];
    if (lane == 0) reds[wid] = sum;
    __syncthreads();
    sum = reds[0] + reds[1] + reds[2] + reds[3];
    const float inv = 1.0f / sum;
#pragma unroll
    for (int i = 0; i < 8; i++) attn[b * 2048 + tid + i * 256] = x[i] * inv;
}

// ---- context[b][e] = sum_s attn[b][s] * enc[b][s][e] ----
__global__ __launch_bounds__(256) void ctx_kern(const float* __restrict__ attn,
                                                const float* __restrict__ enc,
                                                float* __restrict__ out) {
    const int b = blockIdx.y;
    const int sc = blockIdx.x;    // 32 chunks x 64 s
    const int tid = threadIdx.x;
    const float* ab = attn + b * 2048 + sc * 64;
    const float* eb = enc + ((size_t)b * 2048 + sc * 64) * 1024 + tid * 4;
    float4 acc = {0.f, 0.f, 0.f, 0.f};
#pragma unroll 16
    for (int s = 0; s < 64; s++) {
        float w = ab[s];
        float4 ev = *reinterpret_cast<const float4*>(eb + (size_t)s * 1024);
        acc.x = fmaf(w, ev.x, acc.x);
        acc.y = fmaf(w, ev.y, acc.y);
        acc.z = fmaf(w, ev.z, acc.z);
        acc.w = fmaf(w, ev.w, acc.w);
    }
    float* o = out + b * 1024 + tid * 4;
    atomicAdd(o + 0, acc.x);
    atomicAdd(o + 1, acc.y);
    atomicAdd(o + 2, acc.z);
    atomicAdd(o + 3, acc.w);
}

extern "C" void kernel_launch(void* const* d_in, const int* in_sizes, int n_in,
                              void* d_out, int out_size, void* d_ws, size_t ws_size,
                              hipStream_t stream) {
    const float* enc = (const float*)d_in[0];  // 32*2048*1024
    const float* dec = (const float*)d_in[1];  // 32*1*1024
    const float* w1  = (const float*)d_in[2];  // 1024*1024
    const float* b1  = (const float*)d_in[3];  // 1024
    const float* w2  = (const float*)d_in[4];  // 1024*1024
    const float* b2  = (const float*)d_in[5];  // 1024
    const float* v   = (const float*)d_in[6];  // 1024
    // d_in[7] = bv, softmax-invariant, unused
    float* out = (float*)d_out;                // 32*1024

    char* ws = (char*)d_ws;
    unsigned short* w1p = (unsigned short*)ws;                 // 2 MB
    float* qq     = (float*)(ws + (2u << 20));                 // 128 KB
    float* scores = (float*)(ws + (2u << 20) + (128u << 10));  // 256 KB
    float* attn   = scores + M_TOTAL;                          // 256 KB
    unsigned short* encp = (unsigned short*)(ws + (4u << 20)); // 128 MB

    const size_t need = (4ull << 20) + ((size_t)M_TOTAL * KDIM * 2);
    const bool big = ws_size >= need;

    hipMemsetAsync(qq, 0, (128u << 10) + M_TOTAL * sizeof(float), stream);
    hipMemsetAsync(out, 0, 32 * 1024 * sizeof(float), stream);

    pack_w1<<<dim3(32, 32), dim3(32, 32), 0, stream>>>(w1, w1p);
    qq_kern<<<dim3(4, 32, 4), 256, 0, stream>>>(dec, w2, b1, b2, qq);
    if (big) {
        cvt_enc<<<16384, 256, 0, stream>>>(enc, encp);
        score_gemm_dma<<<4096, 256, 0, stream>>>(encp, w1p, qq, v, scores);
    } else {
        score_gemm_fb<<<4096, 256, 0, stream>>>(enc, w1p, qq, v, scores);
    }
    softmax_kern<<<32, 256, 0, stream>>>(scores, attn);
    ctx_kern<<<dim3(32, 32), 256, 0, stream>>>(attn, enc, out);
}